// Round 3
// baseline (130.789 us; speedup 1.0000x reference)
//
#include <hip/hip_runtime.h>
#include <hip/hip_bf16.h>
#include <cstdint>

#define GLOBAL_AS __attribute__((address_space(1)))
#define LDS_AS    __attribute__((address_space(3)))

typedef short s8v  __attribute__((ext_vector_type(8)));
typedef float f4v  __attribute__((ext_vector_type(4)));
typedef unsigned short u8s __attribute__((ext_vector_type(8)));

#define NEGV (-1e7f)

__device__ __forceinline__ void gload_lds16(const void* g, void* l) {
  __builtin_amdgcn_global_load_lds((const GLOBAL_AS uint32_t*)g,
                                   (LDS_AS uint32_t*)l, 16, 0, 0);
}

__device__ __forceinline__ unsigned short f2bf(float f) {
  union { float f; uint32_t u; } v; v.f = f;
  uint32_t u = v.u;
  u += 0x7fffu + ((u >> 16) & 1u);
  return (unsigned short)(u >> 16);
}

// ---------------- convert bert_out (f32) -> bf16, same layout ----------------
__global__ __launch_bounds__(256) void cvt_a(const float* __restrict__ x,
                                             unsigned short* __restrict__ y,
                                             int n8) {
  int i = blockIdx.x * blockDim.x + threadIdx.x;
  int stride = gridDim.x * blockDim.x;
  for (; i < n8; i += stride) {
    float4 a = ((const float4*)x)[2 * i + 0];
    float4 b = ((const float4*)x)[2 * i + 1];
    u8s o;
    o[0] = f2bf(a.x); o[1] = f2bf(a.y); o[2] = f2bf(a.z); o[3] = f2bf(a.w);
    o[4] = f2bf(b.x); o[5] = f2bf(b.y); o[6] = f2bf(b.z); o[7] = f2bf(b.w);
    ((u8s*)y)[i] = o;
  }
}

// ------------- convert + transpose W1 (K x N f32) -> W1T (N x K bf16) -------------
__global__ __launch_bounds__(256) void cvt_w1t(const float* __restrict__ w1,
                                               unsigned short* __restrict__ w1t) {
  __shared__ float tile[32][33];
  int bx = blockIdx.x & 31;   // n-tile
  int by = blockIdx.x >> 5;   // k-tile
  int tx = threadIdx.x & 31;
  int ty = threadIdx.x >> 5;  // 0..7
#pragma unroll
  for (int j = 0; j < 4; ++j) {
    int kk = ty + j * 8;
    tile[kk][tx] = w1[(size_t)(by * 32 + kk) * 1024 + bx * 32 + tx];
  }
  __syncthreads();
#pragma unroll
  for (int j = 0; j < 4; ++j) {
    int nn = ty + j * 8;
    w1t[(size_t)(bx * 32 + nn) * 1024 + by * 32 + tx] = f2bf(tile[tx][nn]);
  }
}

// ---------------- fused GEMM: h = relu(A*W1 + b1); logits += h * W2 ----------------
// 256x256 tile, BK=64, 8 waves (2M x 4N), mfma_f32_16x16x32_bf16.
// 128 KiB double-buffered LDS; counted vmcnt(4); 2 barriers per K-tile with
// 64 MFMA/wave between them. XOR swizzle both-sides (rule 21): LDS[r][b] =
// G[r][b ^ ((r&7)<<4)], linear gload_lds dest + pre-swizzled global source,
// same XOR on ds_read_b128 — measured 0 bank conflicts.
__global__ __launch_bounds__(512, 2) void gemm_fused(
    const unsigned short* __restrict__ Abf,   // [16384][1024] bf16
    const unsigned short* __restrict__ Bbf,   // [1024][1024] bf16 (W1^T)
    const float* __restrict__ b1,
    const float* __restrict__ W2,             // [1024][3] f32
    float* __restrict__ logits)               // [16384][3] f32, pre-zeroed
{
  __shared__ __align__(16) char lds[131072];  // 2 bufs x (32KB A + 32KB B)

  // bijective XCD swizzle: 256 wgs, 8 XCDs, 32 per XCD
  int bid = blockIdx.x;
  int wid = (bid & 7) * 32 + (bid >> 3);
  int mt = wid >> 2;   // 0..63
  int nt = wid & 3;    // 0..3

  int tid  = threadIdx.x;
  int lane = tid & 63;
  int wv   = tid >> 6;  // 0..7
  int wr   = wv >> 2;   // wave row (0..1), 128 rows each
  int wc   = wv & 3;    // wave col (0..3), 64 cols each

  f4v acc[8][4];
#pragma unroll
  for (int m = 0; m < 8; ++m)
#pragma unroll
    for (int n = 0; n < 4; ++n)
      acc[m][n] = f4v{0.f, 0.f, 0.f, 0.f};

  const size_t arow0 = (size_t)mt * 256;
  const size_t brow0 = (size_t)nt * 256;

  // staging: per wave 4 chunks x 1KB per matrix; rows [wv*32, wv*32+32)
  const int scol = ((lane & 7) * 16) ^ ((lane >> 3) << 4);  // pre-swizzled src col

  auto STAGE_A = [&](int t) {
    int k0 = t * 64;
    char* dst = lds + ((t & 1) << 16) + (wv << 12);
#pragma unroll
    for (int c = 0; c < 4; ++c) {
      int rl = wv * 32 + c * 8 + (lane >> 3);
      gload_lds16(Abf + (arow0 + rl) * 1024 + k0 + (scol >> 1), dst + c * 1024);
    }
  };
  auto STAGE_B = [&](int t) {
    int k0 = t * 64;
    char* dst = lds + ((t & 1) << 16) + 32768 + (wv << 12);
#pragma unroll
    for (int c = 0; c < 4; ++c) {
      int rl = wv * 32 + c * 8 + (lane >> 3);
      gload_lds16(Bbf + (brow0 + rl) * 1024 + k0 + (scol >> 1), dst + c * 1024);
    }
  };

  const int klane = (lane >> 4) << 4;  // 0,16,32,48: 16B sub-slice within 64B k-slice

  auto PHASE = [&](int buf, int nb) {   // nb = 0 or 2: two n-frag columns
    const char* As = lds + (buf << 16);
    const char* Bs = As + 32768;
    s8v bv[2][2];
#pragma unroll
    for (int n2 = 0; n2 < 2; ++n2) {
      int rb = wc * 64 + (nb + n2) * 16 + (lane & 15);
      const char* bp = Bs + rb * 128;
      int sw = (rb & 7) << 4;
      bv[n2][0] = *(const s8v*)(bp + (klane ^ sw));
      bv[n2][1] = *(const s8v*)(bp + ((64 + klane) ^ sw));
    }
    __builtin_amdgcn_s_setprio(1);
#pragma unroll
    for (int m = 0; m < 8; ++m) {
      int ra = wr * 128 + m * 16 + (lane & 15);
      const char* ap = As + ra * 128;
      int sw = (ra & 7) << 4;
      s8v a0 = *(const s8v*)(ap + (klane ^ sw));
      s8v a1 = *(const s8v*)(ap + ((64 + klane) ^ sw));
      acc[m][nb + 0] = __builtin_amdgcn_mfma_f32_16x16x32_bf16(a0, bv[0][0], acc[m][nb + 0], 0, 0, 0);
      acc[m][nb + 0] = __builtin_amdgcn_mfma_f32_16x16x32_bf16(a1, bv[0][1], acc[m][nb + 0], 0, 0, 0);
      acc[m][nb + 1] = __builtin_amdgcn_mfma_f32_16x16x32_bf16(a0, bv[1][0], acc[m][nb + 1], 0, 0, 0);
      acc[m][nb + 1] = __builtin_amdgcn_mfma_f32_16x16x32_bf16(a1, bv[1][1], acc[m][nb + 1], 0, 0, 0);
    }
    __builtin_amdgcn_s_setprio(0);
  };

  STAGE_A(0);
  STAGE_B(0);
  for (int t = 0; t < 15; ++t) {
    STAGE_A(t + 1);                                   // tile t+1 A -> buf 1-c
    asm volatile("s_waitcnt vmcnt(4)" ::: "memory");  // tile t fully landed
    __builtin_amdgcn_s_barrier();
    __builtin_amdgcn_sched_barrier(0);
    PHASE(t & 1, 0);
    STAGE_B(t + 1);                                   // tile t+1 B -> buf 1-c
    PHASE(t & 1, 2);
    __builtin_amdgcn_sched_barrier(0);
    __builtin_amdgcn_s_barrier();                     // all reads of buf c done
  }
  asm volatile("s_waitcnt vmcnt(0)" ::: "memory");
  __builtin_amdgcn_s_barrier();
  PHASE(1, 0);
  PHASE(1, 2);

  // epilogue: h = relu(acc + b1); logits += h * W2 (shfl-reduce over 16 lanes)
  float b1v[4];
  float w2v[4][3];
#pragma unroll
  for (int n = 0; n < 4; ++n) {
    int gc = nt * 256 + wc * 64 + n * 16 + (lane & 15);
    b1v[n] = b1[gc];
    w2v[n][0] = W2[gc * 3 + 0];
    w2v[n][1] = W2[gc * 3 + 1];
    w2v[n][2] = W2[gc * 3 + 2];
  }
#pragma unroll
  for (int m = 0; m < 8; ++m) {
#pragma unroll
    for (int q = 0; q < 4; ++q) {
      float p0 = 0.f, p1 = 0.f, p2 = 0.f;
#pragma unroll
      for (int n = 0; n < 4; ++n) {
        float h = acc[m][n][q] + b1v[n];
        h = fmaxf(h, 0.f);
        p0 += h * w2v[n][0];
        p1 += h * w2v[n][1];
        p2 += h * w2v[n][2];
      }
#pragma unroll
      for (int s = 1; s < 16; s <<= 1) {
        p0 += __shfl_xor(p0, s, 64);
        p1 += __shfl_xor(p1, s, 64);
        p2 += __shfl_xor(p2, s, 64);
      }
      if ((lane & 15) == 0) {
        int grow = mt * 256 + wr * 128 + m * 16 + (lane >> 4) * 4 + q;
        atomicAdd(&logits[grow * 3 + 0], p0);
        atomicAdd(&logits[grow * 3 + 1], p1);
        atomicAdd(&logits[grow * 3 + 2], p2);
      }
    }
  }
}

// ---------------- finalize: log-softmax, gather, logsumexp ----------------
__device__ __forceinline__ float blockReduceSum(float v, float* red, int t) {
#pragma unroll
  for (int s = 32; s >= 1; s >>= 1) v += __shfl_xor(v, s, 64);
  __syncthreads();
  if ((t & 63) == 0) red[t >> 6] = v;
  __syncthreads();
  return red[0] + red[1] + red[2] + red[3];
}

__global__ __launch_bounds__(256) void finalize(
    const float* __restrict__ logits,   // [16384][3]
    const float* __restrict__ b2,       // [3]
    const int* __restrict__ seq_mask,   // [32][512]
    const int* __restrict__ ans,        // [32][8][512]
    const int* __restrict__ span,       // [32][512]
    const int* __restrict__ isbio,      // [32]
    float* __restrict__ out)            // [32]
{
  int b = blockIdx.x;
  int t = threadIdx.x;
  __shared__ float lp[512][3];
  __shared__ float red[4];
  __shared__ float seq_ll[9];
  __shared__ int preg;

  float b20 = b2[0], b21 = b2[1], b22 = b2[2];

  for (int l = t; l < 512; l += 256) {
    int gi = b * 512 + l;
    float x0 = logits[gi * 3 + 0] + b20;
    float x1 = logits[gi * 3 + 1] + b21;
    float x2 = logits[gi * 3 + 2] + b22;
    float mx = fmaxf(x0, fmaxf(x1, x2));
    float lse = mx + logf(expf(x0 - mx) + expf(x1 - mx) + expf(x2 - mx));
    float msk = (float)seq_mask[gi];
    lp[l][0] = (x0 - lse) * msk;
    lp[l][1] = (x1 - lse) * msk;
    lp[l][2] = (x2 - lse) * msk;
  }
  __syncthreads();

  // is_pregen = sum(ans * seq_mask) > 0
  float s = 0.f;
  for (int i = t; i < 8 * 512; i += 256) {
    int m = i >> 9, l = i & 511;
    s += (float)(ans[(b * 8 + m) * 512 + l] * seq_mask[b * 512 + l]);
  }
  s = blockReduceSum(s, red, t);
  if (t == 0) preg = (s > 0.f) ? 1 : 0;
  __syncthreads();
  int ip = preg;

  for (int m = 0; m < 9; ++m) {
    float sll = 0.f, sidx = 0.f;
    for (int l = t; l < 512; l += 256) {
      int idx;
      if (m < 8) idx = ans[(b * 8 + m) * 512 + l] * seq_mask[b * 512 + l];
      else       idx = span[b * 512 + l] * (1 - ip);
      sll  += lp[l][idx];
      sidx += (float)idx;
    }
    sll  = blockReduceSum(sll, red, t);
    sidx = blockReduceSum(sidx, red, t);
    if (t == 0) seq_ll[m] = (sidx > 0.f) ? sll : NEGV;
  }

  if (t == 0) {
    float mx = seq_ll[0];
#pragma unroll
    for (int m = 1; m < 9; ++m) mx = fmaxf(mx, seq_ll[m]);
    float sum = 0.f;
#pragma unroll
    for (int m = 0; m < 9; ++m) sum += expf(seq_ll[m] - mx);
    float lml = mx + logf(sum);
    out[b] = isbio[b] ? lml : NEGV;
  }
}

extern "C" void kernel_launch(void* const* d_in, const int* in_sizes, int n_in,
                              void* d_out, int out_size, void* d_ws, size_t ws_size,
                              hipStream_t stream) {
  const float* bert     = (const float*)d_in[0];
  const int*   seq_mask = (const int*)d_in[1];
  // d_in[2] wordpiece_mask: unused
  // d_in[3] answer_as_text_to_disjoint_bios: unused
  const int*   ans      = (const int*)d_in[4];
  const int*   span     = (const int*)d_in[5];
  const int*   isbio    = (const int*)d_in[6];
  const float* W1       = (const float*)d_in[7];
  const float* b1       = (const float*)d_in[8];
  const float* W2       = (const float*)d_in[9];
  const float* b2       = (const float*)d_in[10];
  float* out = (float*)d_out;

  char* ws = (char*)d_ws;
  float* logits          = (float*)ws;                                   // 192 KB
  unsigned short* Abf    = (unsigned short*)(ws + (1 << 20));            // 32 MB
  unsigned short* W1T    = (unsigned short*)(ws + (1 << 20) + (size_t)16384 * 1024 * 2); // 2 MB

  hipMemsetAsync(logits, 0, 16384 * 3 * sizeof(float), stream);
  cvt_a<<<2048, 256, 0, stream>>>(bert, Abf, 16384 * 1024 / 8);
  cvt_w1t<<<1024, 256, 0, stream>>>(W1, W1T);
  gemm_fused<<<256, 512, 0, stream>>>(Abf, W1T, b1, W2, logits);
  finalize<<<32, 256, 0, stream>>>(logits, b2, seq_mask, ans, span, isbio, out);
}

// Round 4
// 129.238 us; speedup vs baseline: 1.0120x; 1.0120x over previous
//
#include <hip/hip_runtime.h>
#include <hip/hip_bf16.h>
#include <cstdint>

#define GLOBAL_AS __attribute__((address_space(1)))
#define LDS_AS    __attribute__((address_space(3)))

typedef short s8v  __attribute__((ext_vector_type(8)));
typedef float f4v  __attribute__((ext_vector_type(4)));
typedef unsigned short u8s __attribute__((ext_vector_type(8)));

#define NEGV (-1e7f)

__device__ __forceinline__ void gload_lds16(const void* g, void* l) {
  __builtin_amdgcn_global_load_lds((const GLOBAL_AS uint32_t*)g,
                                   (LDS_AS uint32_t*)l, 16, 0, 0);
}

__device__ __forceinline__ unsigned short f2bf(float f) {
  union { float f; uint32_t u; } v; v.f = f;
  uint32_t u = v.u;
  u += 0x7fffu + ((u >> 16) & 1u);
  return (unsigned short)(u >> 16);
}

// ---------------- convert bert_out (f32) -> bf16, same layout ----------------
__global__ __launch_bounds__(256) void cvt_a(const float* __restrict__ x,
                                             unsigned short* __restrict__ y,
                                             int n8) {
  int i = blockIdx.x * blockDim.x + threadIdx.x;
  int stride = gridDim.x * blockDim.x;
  for (; i < n8; i += stride) {
    float4 a = ((const float4*)x)[2 * i + 0];
    float4 b = ((const float4*)x)[2 * i + 1];
    u8s o;
    o[0] = f2bf(a.x); o[1] = f2bf(a.y); o[2] = f2bf(a.z); o[3] = f2bf(a.w);
    o[4] = f2bf(b.x); o[5] = f2bf(b.y); o[6] = f2bf(b.z); o[7] = f2bf(b.w);
    ((u8s*)y)[i] = o;
  }
}

// ------------- convert + transpose W1 (K x N f32) -> W1T (N x K bf16) -------------
__global__ __launch_bounds__(256) void cvt_w1t(const float* __restrict__ w1,
                                               unsigned short* __restrict__ w1t) {
  __shared__ float tile[32][33];
  int bx = blockIdx.x & 31;   // n-tile
  int by = blockIdx.x >> 5;   // k-tile
  int tx = threadIdx.x & 31;
  int ty = threadIdx.x >> 5;  // 0..7
#pragma unroll
  for (int j = 0; j < 4; ++j) {
    int kk = ty + j * 8;
    tile[kk][tx] = w1[(size_t)(by * 32 + kk) * 1024 + bx * 32 + tx];
  }
  __syncthreads();
#pragma unroll
  for (int j = 0; j < 4; ++j) {
    int nn = ty + j * 8;
    w1t[(size_t)(bx * 32 + nn) * 1024 + by * 32 + tx] = f2bf(tile[tx][nn]);
  }
}

// ---------------- fused GEMM: h = relu(A*W1 + b1); logits += h * W2 ----------------
// 256x256 tile, BK=64, 8 waves (2M x 4N), 8-phase schedule (T2+T3+T4+T5):
// half-slots of 16KB ({A,B} x {row-half}); per phase: ds_read quadrant frags
// (12/4/8/0 b128) + stage 1 half-slot (2x gload_lds) -> barrier -> 16 MFMA
// (setprio) -> barrier. Counted vmcnt(4) ONLY at phases 4 and 8 (2 slots stay
// in flight across barriers; never drained to 0 in the loop).
// Stage order ph1..8: (T+1,A,h1)(T+1,B,h1)(T+2,B,h0)(T+2,A,h0)(T+2,A,h1)
// (T+2,B,h1)(T+3,B,h0)(T+3,A,h0). Race ledger: every read covered by a
// vmcnt drain >=1 barrier earlier; every overwrite >=1 barrier after last read.
// Overflow stages (tiles >=16) go to a dummy LDS slot to keep vmcnt counts exact.
// XOR swizzle both-sides (rule 21): LDS[r][b]=G[r][b^((r&7)<<4)], measured 0 conflicts.
__global__ __launch_bounds__(512, 2) void gemm_fused(
    const unsigned short* __restrict__ Abf,   // [16384][1024] bf16
    const unsigned short* __restrict__ Bbf,   // [1024][1024] bf16 (W1^T)
    const float* __restrict__ b1,
    const float* __restrict__ W2,             // [1024][3] f32
    float* __restrict__ logits)               // [16384][3] f32, pre-zeroed
{
  __shared__ __align__(16) char lds[147456];  // 2x64KB tile bufs + 16KB dummy

  // bijective XCD swizzle: 256 wgs, 8 XCDs, 32 per XCD
  int bid = blockIdx.x;
  int wid = (bid & 7) * 32 + (bid >> 3);
  int mt = wid >> 2;   // 0..63
  int nt = wid & 3;    // 0..3

  int tid  = threadIdx.x;
  int lane = tid & 63;
  int wv   = tid >> 6;  // 0..7
  int wr   = wv >> 2;   // wave row (0..1): rows wr*128..+127
  int wc   = wv & 3;    // wave col (0..3): cols wc*64..+63

  int laneq = lane & 15;
  int klo   = (lane >> 4) << 4;          // 0,16,32,48
  int sw    = (laneq & 7) << 4;          // row-derived XOR (row&7 == laneq&7)
  int x0    = klo ^ sw;                  // kh=0 byte offset within 128B row
  int x1    = (64 + klo) ^ sw;           // kh=1

  const size_t arow0 = (size_t)mt * 256;
  const size_t brow0 = (size_t)nt * 256;

  // staging per-lane source base: row (lane>>3), pre-swizzled col
  int scol = ((lane & 7) * 16) ^ ((lane >> 3) << 4);
  const unsigned short* gA = Abf + (arow0 + (lane >> 3)) * 1024 + (scol >> 1)
                                 + (size_t)wv * 16 * 1024;
  const unsigned short* gB = Bbf + (brow0 + (lane >> 3)) * 1024 + (scol >> 1)
                                 + (size_t)wv * 16 * 1024;

  f4v acc[8][4];
#pragma unroll
  for (int m = 0; m < 8; ++m)
#pragma unroll
    for (int n = 0; n < 4; ++n)
      acc[m][n] = f4v{0.f, 0.f, 0.f, 0.f};

  s8v a_frag[4][2];      // current m-quadrant, 2 k-halves
  s8v b_frag[2][2][2];   // [npair][n2][kh]

  // stage one 16KB half-slot: 2 x gload_lds per thread (8 rows each)
  auto STAGE = [&](int ts, int isB, int rh) {
    int ok  = ts < 16;
    int tcl = ok ? ts : 15;
    const unsigned short* g = (isB ? gB : gA) + (size_t)rh * 128 * 1024 + tcl * 64;
    int dst = ok ? (((tcl & 1) << 16) | (isB << 15) | (rh << 14) | (wv << 11))
                 : (131072 + (wv << 11));
    gload_lds16(g,            lds + dst);
    gload_lds16(g + 8 * 1024, lds + dst + 1024);
  };

  auto READ_A = [&](int buf, int mq) {
    const char* p = lds + (buf << 16) + (wr << 14) + laneq * 128 + mq * 8192;
#pragma unroll
    for (int m = 0; m < 4; ++m) {
      a_frag[m][0] = *(const s8v*)(p + m * 2048 + x0);
      a_frag[m][1] = *(const s8v*)(p + m * 2048 + x1);
    }
  };
  auto READ_B = [&](int buf, int np) {
    const char* p = lds + (buf << 16) + 32768 + ((wc >> 1) << 14)
                        + ((wc & 1) * 64 + laneq) * 128 + np * 4096;
#pragma unroll
    for (int n2 = 0; n2 < 2; ++n2) {
      b_frag[np][n2][0] = *(const s8v*)(p + n2 * 2048 + x0);
      b_frag[np][n2][1] = *(const s8v*)(p + n2 * 2048 + x1);
    }
  };
  auto MFMA_Q = [&](int mq, int np) {
    __builtin_amdgcn_s_setprio(1);
#pragma unroll
    for (int m = 0; m < 4; ++m)
#pragma unroll
      for (int n2 = 0; n2 < 2; ++n2) {
        acc[mq*4+m][np*2+n2] = __builtin_amdgcn_mfma_f32_16x16x32_bf16(
            a_frag[m][0], b_frag[np][n2][0], acc[mq*4+m][np*2+n2], 0, 0, 0);
        acc[mq*4+m][np*2+n2] = __builtin_amdgcn_mfma_f32_16x16x32_bf16(
            a_frag[m][1], b_frag[np][n2][1], acc[mq*4+m][np*2+n2], 0, 0, 0);
      }
    __builtin_amdgcn_s_setprio(0);
  };

#define BAR  __builtin_amdgcn_s_barrier()
#define SB0  __builtin_amdgcn_sched_barrier(0)
#define VM4  asm volatile("s_waitcnt vmcnt(4)" ::: "memory")

  // prologue: tile0 all 4 slots + tile1 {B,h0},{A,h0}; drain tile0, keep 2 in flight
  STAGE(0,1,0); STAGE(0,0,0); STAGE(0,0,1); STAGE(0,1,1);
  STAGE(1,1,0); STAGE(1,0,0);
  VM4; BAR;

  for (int i = 0; i < 8; ++i) {
    int T = 2 * i;
    // ---- tile T (buf 0) ----
    READ_A(0,0); READ_B(0,0); STAGE(T+1,0,1);
    BAR; SB0; MFMA_Q(0,0); SB0; BAR;
    READ_B(0,1);             STAGE(T+1,1,1);
    BAR; SB0; MFMA_Q(0,1); SB0; BAR;
    READ_A(0,1);             STAGE(T+2,1,0);
    BAR; SB0; MFMA_Q(1,1); SB0; BAR;
                             STAGE(T+2,0,0);
    VM4;
    BAR; SB0; MFMA_Q(1,0); SB0; BAR;
    // ---- tile T+1 (buf 1) ----
    READ_A(1,0); READ_B(1,0); STAGE(T+2,0,1);
    BAR; SB0; MFMA_Q(0,0); SB0; BAR;
    READ_B(1,1);             STAGE(T+2,1,1);
    BAR; SB0; MFMA_Q(0,1); SB0; BAR;
    READ_A(1,1);             STAGE(T+3,1,0);
    BAR; SB0; MFMA_Q(1,1); SB0; BAR;
                             STAGE(T+3,0,0);
    VM4;
    BAR; SB0; MFMA_Q(1,0); SB0; BAR;
  }

#undef BAR
#undef SB0
#undef VM4

  // epilogue: h = relu(acc + b1); logits += h * W2 (shfl-reduce over 16 lanes)
  float b1v[4];
  float w2v[4][3];
#pragma unroll
  for (int n = 0; n < 4; ++n) {
    int gc = nt * 256 + wc * 64 + n * 16 + laneq;
    b1v[n] = b1[gc];
    w2v[n][0] = W2[gc * 3 + 0];
    w2v[n][1] = W2[gc * 3 + 1];
    w2v[n][2] = W2[gc * 3 + 2];
  }
#pragma unroll
  for (int m = 0; m < 8; ++m) {
#pragma unroll
    for (int q = 0; q < 4; ++q) {
      float p0 = 0.f, p1 = 0.f, p2 = 0.f;
#pragma unroll
      for (int n = 0; n < 4; ++n) {
        float h = acc[m][n][q] + b1v[n];
        h = fmaxf(h, 0.f);
        p0 += h * w2v[n][0];
        p1 += h * w2v[n][1];
        p2 += h * w2v[n][2];
      }
#pragma unroll
      for (int s = 1; s < 16; s <<= 1) {
        p0 += __shfl_xor(p0, s, 64);
        p1 += __shfl_xor(p1, s, 64);
        p2 += __shfl_xor(p2, s, 64);
      }
      if ((lane & 15) == 0) {
        int grow = mt * 256 + wr * 128 + m * 16 + (lane >> 4) * 4 + q;
        atomicAdd(&logits[grow * 3 + 0], p0);
        atomicAdd(&logits[grow * 3 + 1], p1);
        atomicAdd(&logits[grow * 3 + 2], p2);
      }
    }
  }
}

// ---------------- finalize: log-softmax, gather, logsumexp ----------------
__device__ __forceinline__ float blockReduceSum(float v, float* red, int t) {
#pragma unroll
  for (int s = 32; s >= 1; s >>= 1) v += __shfl_xor(v, s, 64);
  __syncthreads();
  if ((t & 63) == 0) red[t >> 6] = v;
  __syncthreads();
  return red[0] + red[1] + red[2] + red[3];
}

__global__ __launch_bounds__(256) void finalize(
    const float* __restrict__ logits,   // [16384][3]
    const float* __restrict__ b2,       // [3]
    const int* __restrict__ seq_mask,   // [32][512]
    const int* __restrict__ ans,        // [32][8][512]
    const int* __restrict__ span,       // [32][512]
    const int* __restrict__ isbio,      // [32]
    float* __restrict__ out)            // [32]
{
  int b = blockIdx.x;
  int t = threadIdx.x;
  __shared__ float lp[512][3];
  __shared__ float red[4];
  __shared__ float seq_ll[9];
  __shared__ int preg;

  float b20 = b2[0], b21 = b2[1], b22 = b2[2];

  for (int l = t; l < 512; l += 256) {
    int gi = b * 512 + l;
    float x0 = logits[gi * 3 + 0] + b20;
    float x1 = logits[gi * 3 + 1] + b21;
    float x2 = logits[gi * 3 + 2] + b22;
    float mx = fmaxf(x0, fmaxf(x1, x2));
    float lse = mx + logf(expf(x0 - mx) + expf(x1 - mx) + expf(x2 - mx));
    float msk = (float)seq_mask[gi];
    lp[l][0] = (x0 - lse) * msk;
    lp[l][1] = (x1 - lse) * msk;
    lp[l][2] = (x2 - lse) * msk;
  }
  __syncthreads();

  // is_pregen = sum(ans * seq_mask) > 0
  float s = 0.f;
  for (int i = t; i < 8 * 512; i += 256) {
    int m = i >> 9, l = i & 511;
    s += (float)(ans[(b * 8 + m) * 512 + l] * seq_mask[b * 512 + l]);
  }
  s = blockReduceSum(s, red, t);
  if (t == 0) preg = (s > 0.f) ? 1 : 0;
  __syncthreads();
  int ip = preg;

  for (int m = 0; m < 9; ++m) {
    float sll = 0.f, sidx = 0.f;
    for (int l = t; l < 512; l += 256) {
      int idx;
      if (m < 8) idx = ans[(b * 8 + m) * 512 + l] * seq_mask[b * 512 + l];
      else       idx = span[b * 512 + l] * (1 - ip);
      sll  += lp[l][idx];
      sidx += (float)idx;
    }
    sll  = blockReduceSum(sll, red, t);
    sidx = blockReduceSum(sidx, red, t);
    if (t == 0) seq_ll[m] = (sidx > 0.f) ? sll : NEGV;
  }

  if (t == 0) {
    float mx = seq_ll[0];
#pragma unroll
    for (int m = 1; m < 9; ++m) mx = fmaxf(mx, seq_ll[m]);
    float sum = 0.f;
#pragma unroll
    for (int m = 0; m < 9; ++m) sum += expf(seq_ll[m] - mx);
    float lml = mx + logf(sum);
    out[b] = isbio[b] ? lml : NEGV;
  }
}

extern "C" void kernel_launch(void* const* d_in, const int* in_sizes, int n_in,
                              void* d_out, int out_size, void* d_ws, size_t ws_size,
                              hipStream_t stream) {
  const float* bert     = (const float*)d_in[0];
  const int*   seq_mask = (const int*)d_in[1];
  // d_in[2] wordpiece_mask: unused
  // d_in[3] answer_as_text_to_disjoint_bios: unused
  const int*   ans      = (const int*)d_in[4];
  const int*   span     = (const int*)d_in[5];
  const int*   isbio    = (const int*)d_in[6];
  const float* W1       = (const float*)d_in[7];
  const float* b1       = (const float*)d_in[8];
  const float* W2       = (const float*)d_in[9];
  const float* b2       = (const float*)d_in[10];
  float* out = (float*)d_out;

  char* ws = (char*)d_ws;
  float* logits          = (float*)ws;                                   // 192 KB
  unsigned short* Abf    = (unsigned short*)(ws + (1 << 20));            // 32 MB
  unsigned short* W1T    = (unsigned short*)(ws + (1 << 20) + (size_t)16384 * 1024 * 2); // 2 MB

  hipMemsetAsync(logits, 0, 16384 * 3 * sizeof(float), stream);
  cvt_a<<<2048, 256, 0, stream>>>(bert, Abf, 16384 * 1024 / 8);
  cvt_w1t<<<1024, 256, 0, stream>>>(W1, W1T);
  gemm_fused<<<256, 512, 0, stream>>>(Abf, W1T, b1, W2, logits);
  finalize<<<32, 256, 0, stream>>>(logits, b2, seq_mask, ans, span, isbio, out);
}